// Round 1
// baseline (159.442 us; speedup 1.0000x reference)
//
#include <hip/hip_runtime.h>
#include <math.h>

#define EPSF   1e-8f
#define NV4    2645760   // 512*6890*3 / 4
#define PER_B  20670     // 6890*3
#define VBLK   2048

// block-role layout (proc first so its long serial work overlaps the stream)
#define B_PROC   0      // 2 blocks  (512 threads, 1 batch each)
#define B_NV     2      // 2 blocks  (512)
#define B_BETA   4      // 20 blocks (5120)
#define B_KP2D   24     // 48 blocks (12288)
#define B_KP3D   72     // 48 blocks (12288)
#define B_POSE   120    // 432 blocks (110592)
#define B_VERT   552    // 2048 blocks
#define NBLK     2600

// ws layout (doubles): 0 shape, 1 pose, 2 kp2d, 3 kp3d, 4 betas, 5 nvalid, 6 pa

__device__ __forceinline__ void block_sum_atomic(float v, double* slot) {
  #pragma unroll
  for (int off = 32; off > 0; off >>= 1) v += __shfl_down(v, off);
  __shared__ float red[4];
  const int lane = threadIdx.x & 63;
  const int wid  = threadIdx.x >> 6;
  if (lane == 0) red[wid] = v;
  __syncthreads();
  if (threadIdx.x == 0) {
    float s = red[0] + red[1] + red[2] + red[3];
    atomicAdd(slot, (double)s);
  }
}

// one Jacobi rotation on symmetric A zeroing A[P][Q]; accumulates V <- V*J
template<int P, int Q>
__device__ __forceinline__ void jrot(float A[3][3], float Vv[3][3]) {
  float apq = A[P][Q];
  if (fabsf(apq) < 1e-20f) return;
  float tau = (A[Q][Q] - A[P][P]) / (2.f * apq);
  float t   = copysignf(1.f, tau) / (fabsf(tau) + sqrtf(1.f + tau * tau));
  float c   = 1.f / sqrtf(1.f + t * t);
  float s   = t * c;
  float cP[3], cQ[3];
  #pragma unroll
  for (int k = 0; k < 3; ++k) { cP[k] = c*A[k][P] - s*A[k][Q]; cQ[k] = s*A[k][P] + c*A[k][Q]; }
  #pragma unroll
  for (int k = 0; k < 3; ++k) { A[k][P] = cP[k]; A[k][Q] = cQ[k]; }
  float rP[3], rQ[3];
  #pragma unroll
  for (int k = 0; k < 3; ++k) { rP[k] = c*A[P][k] - s*A[Q][k]; rQ[k] = s*A[P][k] + c*A[Q][k]; }
  #pragma unroll
  for (int k = 0; k < 3; ++k) { A[P][k] = rP[k]; A[Q][k] = rQ[k]; }
  #pragma unroll
  for (int k = 0; k < 3; ++k) {
    float vp = c*Vv[k][P] - s*Vv[k][Q];
    Vv[k][Q] = s*Vv[k][P] + c*Vv[k][Q];
    Vv[k][P] = vp;
  }
}

#define CSWAP(I, J)                                                        \
  if (lam[I] < lam[J]) {                                                   \
    float tl = lam[I]; lam[I] = lam[J]; lam[J] = tl;                       \
    _Pragma("unroll")                                                      \
    for (int r = 0; r < 3; ++r) {                                          \
      float tv = Vv[r][I]; Vv[r][I] = Vv[r][J]; Vv[r][J] = tv;             \
    }                                                                      \
  }

// per-batch Procrustes: returns sum_j ||scale*R*p_j + t - g_j||
__device__ float procrustes_err(const float* __restrict__ PJall,
                                const float* __restrict__ Gall, int b) {
  const float* P = PJall + b * 72;   // (24,3)
  const float* G = Gall  + b * 96;   // (24,4), use [:, :3]

  float mu1x=0, mu1y=0, mu1z=0, mu2x=0, mu2y=0, mu2z=0;
  for (int j = 0; j < 24; ++j) {
    mu1x += P[j*3+0]; mu1y += P[j*3+1]; mu1z += P[j*3+2];
    mu2x += G[j*4+0]; mu2y += G[j*4+1]; mu2z += G[j*4+2];
  }
  mu1x /= 24.f; mu1y /= 24.f; mu1z /= 24.f;
  mu2x /= 24.f; mu2y /= 24.f; mu2z /= 24.f;

  float K[3][3] = {{0,0,0},{0,0,0},{0,0,0}};
  float var1 = 0.f;
  for (int j = 0; j < 24; ++j) {
    float x0 = P[j*3+0]-mu1x, x1 = P[j*3+1]-mu1y, x2 = P[j*3+2]-mu1z;
    float y0 = G[j*4+0]-mu2x, y1 = G[j*4+1]-mu2y, y2 = G[j*4+2]-mu2z;
    var1 += x0*x0 + x1*x1 + x2*x2;
    K[0][0]+=x0*y0; K[0][1]+=x0*y1; K[0][2]+=x0*y2;
    K[1][0]+=x1*y0; K[1][1]+=x1*y1; K[1][2]+=x1*y2;
    K[2][0]+=x2*y0; K[2][1]+=x2*y1; K[2][2]+=x2*y2;
  }
  #pragma unroll
  for (int r = 0; r < 3; ++r)
    #pragma unroll
    for (int c = 0; c < 3; ++c) K[r][c] += EPSF;

  float detK = K[0][0]*(K[1][1]*K[2][2]-K[1][2]*K[2][1])
             - K[0][1]*(K[1][0]*K[2][2]-K[1][2]*K[2][0])
             + K[0][2]*(K[1][0]*K[2][1]-K[1][1]*K[2][0]);
  float sgn = (detK > 0.f) ? 1.f : ((detK < 0.f) ? -1.f : 0.f);

  // A = K^T K  (eigvecs of A = right singular vectors V)
  float A[3][3];
  #pragma unroll
  for (int r = 0; r < 3; ++r)
    #pragma unroll
    for (int c = 0; c < 3; ++c)
      A[r][c] = K[0][r]*K[0][c] + K[1][r]*K[1][c] + K[2][r]*K[2][c];

  float Vv[3][3] = {{1,0,0},{0,1,0},{0,0,1}};
  for (int sweep = 0; sweep < 8; ++sweep) {
    jrot<0,1>(A, Vv); jrot<0,2>(A, Vv); jrot<1,2>(A, Vv);
  }
  float lam[3] = {A[0][0], A[1][1], A[2][2]};
  CSWAP(0,1) CSWAP(0,2) CSWAP(1,2)   // descending

  // R = sum_i z_i/s_i * v_i (K v_i)^T ;  trace(RK) = sum_i z_i s_i
  float Rm[3][3] = {{0,0,0},{0,0,0},{0,0,0}};
  float zi[3] = {1.f, 1.f, sgn};
  float trRK = 0.f;
  #pragma unroll
  for (int i = 0; i < 3; ++i) {
    float v0 = Vv[0][i], v1 = Vv[1][i], v2 = Vv[2][i];
    float a0 = K[0][0]*v0 + K[0][1]*v1 + K[0][2]*v2;
    float a1 = K[1][0]*v0 + K[1][1]*v1 + K[1][2]*v2;
    float a2 = K[2][0]*v0 + K[2][1]*v1 + K[2][2]*v2;
    float si = sqrtf(a0*a0 + a1*a1 + a2*a2);
    float zs = zi[i] / fmaxf(si, 1e-20f);
    Rm[0][0]+=zs*v0*a0; Rm[0][1]+=zs*v0*a1; Rm[0][2]+=zs*v0*a2;
    Rm[1][0]+=zs*v1*a0; Rm[1][1]+=zs*v1*a1; Rm[1][2]+=zs*v1*a2;
    Rm[2][0]+=zs*v2*a0; Rm[2][1]+=zs*v2*a1; Rm[2][2]+=zs*v2*a2;
    trRK += zi[i] * si;
  }
  float scale = trRK / var1;
  float t0 = mu2x - scale*(Rm[0][0]*mu1x + Rm[0][1]*mu1y + Rm[0][2]*mu1z);
  float t1 = mu2y - scale*(Rm[1][0]*mu1x + Rm[1][1]*mu1y + Rm[1][2]*mu1z);
  float t2 = mu2z - scale*(Rm[2][0]*mu1x + Rm[2][1]*mu1y + Rm[2][2]*mu1z);

  float errsum = 0.f;
  for (int j = 0; j < 24; ++j) {
    float px = P[j*3+0], py = P[j*3+1], pz = P[j*3+2];
    float q0 = scale*(Rm[0][0]*px + Rm[0][1]*py + Rm[0][2]*pz) + t0;
    float q1 = scale*(Rm[1][0]*px + Rm[1][1]*py + Rm[1][2]*pz) + t1;
    float q2 = scale*(Rm[2][0]*px + Rm[2][1]*py + Rm[2][2]*pz) + t2;
    float d0 = q0 - G[j*4+0], d1 = q1 - G[j*4+1], d2 = q2 - G[j*4+2];
    errsum += sqrtf(d0*d0 + d1*d1 + d2*d2);
  }
  return errsum;
}

__global__ __launch_bounds__(256) void bmp_main(
    const float*  __restrict__ pred_rotmat, const float* __restrict__ pred_camera,
    const float*  __restrict__ pred_joints, const float4* __restrict__ pred_verts,
    const float*  __restrict__ pred_betas,  const float* __restrict__ gt_rotmat,
    const float*  __restrict__ gt_shape,    const float* __restrict__ gt_kp2d,
    const float*  __restrict__ gt_kp3d,     const float4* __restrict__ gt_verts,
    const int*    __restrict__ has_smpl,    double* __restrict__ ws) {
  const int bid = blockIdx.x;
  const int tid = threadIdx.x;

  if (bid >= B_VERT) {                       // ---- vertex |diff| stream ----
    float acc = 0.f;
    for (int i = (bid - B_VERT) * 256 + tid; i < NV4; i += VBLK * 256) {
      float4 a = pred_verts[i];
      float4 b = gt_verts[i];
      int e  = i * 4;
      int b0 = e / PER_B;
      int b3 = (e + 3) / PER_B;
      if (b0 == b3) {
        if (has_smpl[b0] > 0)
          acc += fabsf(a.x-b.x) + fabsf(a.y-b.y) + fabsf(a.z-b.z) + fabsf(a.w-b.w);
      } else {
        float d[4] = {fabsf(a.x-b.x), fabsf(a.y-b.y), fabsf(a.z-b.z), fabsf(a.w-b.w)};
        #pragma unroll
        for (int c = 0; c < 4; ++c) {
          int bb = (e + c) / PER_B;
          if (has_smpl[bb] > 0) acc += d[c];
        }
      }
    }
    block_sum_atomic(acc, &ws[0]);
    return;
  }

  if (bid >= B_POSE) {                       // ---- pose: mask*(dR)^2 ----
    int idx = (bid - B_POSE) * 256 + tid;    // < 110592
    int b   = idx / 216;
    float m = (has_smpl[b] > 0) ? 1.f : 0.f;
    float d = pred_rotmat[idx] - gt_rotmat[idx];
    block_sum_atomic(m * d * d, &ws[1]);
    return;
  }

  if (bid >= B_KP3D) {                       // ---- kp3d ----
    int idx = (bid - B_KP3D) * 256 + tid;    // < 12288
    int b = idx / 24, j = idx - (idx / 24) * 24;
    const float* PJ = pred_joints + b * 72;
    const float* G  = gt_kp3d + b * 96;
    float cf = G[j*4+3];
    float ssum = 0.f;
    #pragma unroll
    for (int c = 0; c < 3; ++c) {
      float prp = 0.5f * (PJ[2*3+c] + PJ[3*3+c]);
      float gtp = 0.5f * (G[2*4+c] + G[3*4+c]);
      ssum += fabsf((PJ[j*3+c] - prp) - (G[j*4+c] - gtp));
    }
    block_sum_atomic(cf * ssum, &ws[3]);
    return;
  }

  if (bid >= B_KP2D) {                       // ---- kp2d ----
    int idx = (bid - B_KP2D) * 256 + tid;    // < 12288
    int b = idx / 24, j = idx - (idx / 24) * 24;
    float cam0 = pred_camera[b*3+0], cam1 = pred_camera[b*3+1], cam2 = pred_camera[b*3+2];
    float depth = 2.f * 1000.f / (EPSF + cam0 * 512.f);
    float px = pred_joints[(b*24+j)*3+0] + cam1;
    float py = pred_joints[(b*24+j)*3+1] + cam2;
    float pz = pred_joints[(b*24+j)*3+2] + depth;
    float kxn = (1000.f * px / pz + 256.f) * (1.f / 512.f);
    float kyn = (1000.f * py / pz + 256.f) * (1.f / 512.f);
    float gx = gt_kp2d[(b*24+j)*3+0] * (1.f / 512.f);
    float gy = gt_kp2d[(b*24+j)*3+1] * (1.f / 512.f);
    float cf = gt_kp2d[(b*24+j)*3+2];
    block_sum_atomic(cf * (fabsf(kxn - gx) + fabsf(kyn - gy)), &ws[2]);
    return;
  }

  if (bid >= B_BETA) {                       // ---- betas ----
    int idx = (bid - B_BETA) * 256 + tid;    // < 5120
    int b = idx / 10;
    float m = (has_smpl[b] > 0) ? 1.f : 0.f;
    float d = pred_betas[idx] - gt_shape[idx];
    block_sum_atomic(m * d * d, &ws[4]);
    return;
  }

  if (bid >= B_NV) {                         // ---- n_valid ----
    int idx = (bid - B_NV) * 256 + tid;      // < 512
    block_sum_atomic((has_smpl[idx] > 0) ? 1.f : 0.f, &ws[5]);
    return;
  }

  {                                          // ---- Procrustes (2 blocks) ----
    int b = bid * 256 + tid;                 // < 512
    float e = procrustes_err(pred_joints, gt_kp3d, b);
    block_sum_atomic(e, &ws[6]);
  }
}

__global__ void bmp_finalize(const double* __restrict__ ws, float* __restrict__ out) {
  if (threadIdx.x != 0 || blockIdx.x != 0) return;
  double nv = ws[5];
  double loss_kp2d  = ws[2] / 24576.0;              // 512*24*2
  double loss_kp3d  = ws[3] / 36864.0;              // 512*24*3
  double loss_shape = ws[0] / (nv * 20670.0 + 1e-8);
  double loss_pose  = ws[1] / (nv * 216.0   + 1e-8);
  double loss_betas = ws[4] / (nv * 10.0    + 1e-8);
  double pa         = ws[6] / 12288.0;              // 512*24
  out[0] = (float)(4.0*loss_kp2d + 4.0*loss_kp3d + loss_shape + loss_pose
                   + 0.01*loss_betas + pa);
}

extern "C" void kernel_launch(void* const* d_in, const int* in_sizes, int n_in,
                              void* d_out, int out_size, void* d_ws, size_t ws_size,
                              hipStream_t stream) {
  const float*  pred_rotmat = (const float*)d_in[0];
  const float*  pred_camera = (const float*)d_in[1];
  const float*  pred_joints = (const float*)d_in[2];
  const float4* pred_verts  = (const float4*)d_in[3];
  const float*  pred_betas  = (const float*)d_in[4];
  const float*  gt_rotmat   = (const float*)d_in[5];
  const float*  gt_shape    = (const float*)d_in[6];
  const float*  gt_kp2d     = (const float*)d_in[7];
  const float*  gt_kp3d     = (const float*)d_in[8];
  const float4* gt_verts    = (const float4*)d_in[9];
  const int*    has_smpl    = (const int*)d_in[10];
  double* ws = (double*)d_ws;

  hipMemsetAsync(d_ws, 0, 7 * sizeof(double), stream);
  bmp_main<<<NBLK, 256, 0, stream>>>(pred_rotmat, pred_camera, pred_joints,
      pred_verts, pred_betas, gt_rotmat, gt_shape, gt_kp2d, gt_kp3d, gt_verts,
      has_smpl, ws);
  bmp_finalize<<<1, 64, 0, stream>>>(ws, (float*)d_out);
}

// Round 2
// 148.326 us; speedup vs baseline: 1.0749x; 1.0749x over previous
//
#include <hip/hip_runtime.h>
#include <math.h>

#define EPSF   1e-8f
#define NV4    2645760   // 512*6890*3 / 4
#define PER_B  20670     // 6890*3
#define VBLK   2048

// block-role layout. ws[bid] = this block's partial (double). No atomics, no init.
#define B_PROC   0      // 8 blocks, 64 active threads each -> 512 batches
#define B_NV     8      // 2 blocks
#define B_BETA   10     // 20 blocks (5120)
#define B_KP2D   30     // 48 blocks (12288)
#define B_KP3D   78     // 48 blocks (12288)
#define B_POSE   126    // 432 blocks (110592)
#define B_VERT   558    // 2048 blocks (vertex stream)
#define NBLK     2606

// finalize slots: 0 shape, 1 pose, 2 kp3d, 3 kp2d, 4 betas, 5 nvalid, 6 pa

__device__ __forceinline__ void block_sum_store(float v, double* dst) {
  #pragma unroll
  for (int off = 32; off > 0; off >>= 1) v += __shfl_down(v, off);
  __shared__ float red[4];
  const int lane = threadIdx.x & 63;
  const int wid  = threadIdx.x >> 6;
  if (lane == 0) red[wid] = v;
  __syncthreads();
  if (threadIdx.x == 0) *dst = (double)(red[0] + red[1] + red[2] + red[3]);
}

// one Jacobi rotation on symmetric A zeroing A[P][Q]; accumulates V <- V*J
template<int P, int Q>
__device__ __forceinline__ void jrot(float A[3][3], float Vv[3][3]) {
  float apq = A[P][Q];
  if (fabsf(apq) < 1e-20f) return;
  float tau = (A[Q][Q] - A[P][P]) / (2.f * apq);
  float t   = copysignf(1.f, tau) / (fabsf(tau) + sqrtf(1.f + tau * tau));
  float c   = 1.f / sqrtf(1.f + t * t);
  float s   = t * c;
  float cP[3], cQ[3];
  #pragma unroll
  for (int k = 0; k < 3; ++k) { cP[k] = c*A[k][P] - s*A[k][Q]; cQ[k] = s*A[k][P] + c*A[k][Q]; }
  #pragma unroll
  for (int k = 0; k < 3; ++k) { A[k][P] = cP[k]; A[k][Q] = cQ[k]; }
  float rP[3], rQ[3];
  #pragma unroll
  for (int k = 0; k < 3; ++k) { rP[k] = c*A[P][k] - s*A[Q][k]; rQ[k] = s*A[P][k] + c*A[Q][k]; }
  #pragma unroll
  for (int k = 0; k < 3; ++k) { A[P][k] = rP[k]; A[Q][k] = rQ[k]; }
  #pragma unroll
  for (int k = 0; k < 3; ++k) {
    float vp = c*Vv[k][P] - s*Vv[k][Q];
    Vv[k][Q] = s*Vv[k][P] + c*Vv[k][Q];
    Vv[k][P] = vp;
  }
}

#define CSWAP(I, J)                                                        \
  if (lam[I] < lam[J]) {                                                   \
    float tl = lam[I]; lam[I] = lam[J]; lam[J] = tl;                       \
    _Pragma("unroll")                                                      \
    for (int r = 0; r < 3; ++r) {                                          \
      float tv = Vv[r][I]; Vv[r][I] = Vv[r][J]; Vv[r][J] = tv;             \
    }                                                                      \
  }

// per-batch Procrustes via float4 gathers; single pass moments, re-load for error
__device__ float procrustes_err(const float4* __restrict__ P4,
                                const float4* __restrict__ G4, int b) {
  const float4* Pr = P4 + b * 18;   // 24 joints * 3 = 72 floats = 18 float4
  const float4* Gr = G4 + b * 24;   // 24 joints * 4 = 96 floats = 24 float4

  float sx0=0,sx1=0,sx2=0, sy0=0,sy1=0,sy2=0, sxx=0;
  float Ku[3][3] = {{0,0,0},{0,0,0},{0,0,0}};
  #pragma unroll
  for (int g = 0; g < 6; ++g) {
    float4 p0 = Pr[g*3+0], p1 = Pr[g*3+1], p2 = Pr[g*3+2];
    float px[4][3] = {{p0.x,p0.y,p0.z},{p0.w,p1.x,p1.y},
                      {p1.z,p1.w,p2.x},{p2.y,p2.z,p2.w}};
    #pragma unroll
    for (int q = 0; q < 4; ++q) {
      float4 gg = Gr[g*4+q];
      float x0 = px[q][0], x1 = px[q][1], x2 = px[q][2];
      sx0 += x0; sx1 += x1; sx2 += x2;
      sy0 += gg.x; sy1 += gg.y; sy2 += gg.z;
      sxx += x0*x0 + x1*x1 + x2*x2;
      Ku[0][0]+=x0*gg.x; Ku[0][1]+=x0*gg.y; Ku[0][2]+=x0*gg.z;
      Ku[1][0]+=x1*gg.x; Ku[1][1]+=x1*gg.y; Ku[1][2]+=x1*gg.z;
      Ku[2][0]+=x2*gg.x; Ku[2][1]+=x2*gg.y; Ku[2][2]+=x2*gg.z;
    }
  }
  const float inv24 = 1.f / 24.f;
  float mu1x=sx0*inv24, mu1y=sx1*inv24, mu1z=sx2*inv24;
  float mu2x=sy0*inv24, mu2y=sy1*inv24, mu2z=sy2*inv24;
  float m1[3] = {mu1x, mu1y, mu1z};
  float m2[3] = {mu2x, mu2y, mu2z};
  float K[3][3];
  #pragma unroll
  for (int r = 0; r < 3; ++r)
    #pragma unroll
    for (int c = 0; c < 3; ++c)
      K[r][c] = Ku[r][c] - 24.f * m1[r] * m2[c] + EPSF;
  float var1 = sxx - 24.f * (mu1x*mu1x + mu1y*mu1y + mu1z*mu1z);

  float detK = K[0][0]*(K[1][1]*K[2][2]-K[1][2]*K[2][1])
             - K[0][1]*(K[1][0]*K[2][2]-K[1][2]*K[2][0])
             + K[0][2]*(K[1][0]*K[2][1]-K[1][1]*K[2][0]);
  float sgn = (detK > 0.f) ? 1.f : ((detK < 0.f) ? -1.f : 0.f);

  float A[3][3];
  #pragma unroll
  for (int r = 0; r < 3; ++r)
    #pragma unroll
    for (int c = 0; c < 3; ++c)
      A[r][c] = K[0][r]*K[0][c] + K[1][r]*K[1][c] + K[2][r]*K[2][c];

  float Vv[3][3] = {{1,0,0},{0,1,0},{0,0,1}};
  for (int sweep = 0; sweep < 8; ++sweep) {
    jrot<0,1>(A, Vv); jrot<0,2>(A, Vv); jrot<1,2>(A, Vv);
  }
  float lam[3] = {A[0][0], A[1][1], A[2][2]};
  CSWAP(0,1) CSWAP(0,2) CSWAP(1,2)

  float Rm[3][3] = {{0,0,0},{0,0,0},{0,0,0}};
  float zi[3] = {1.f, 1.f, sgn};
  float trRK = 0.f;
  #pragma unroll
  for (int i = 0; i < 3; ++i) {
    float v0 = Vv[0][i], v1 = Vv[1][i], v2 = Vv[2][i];
    float a0 = K[0][0]*v0 + K[0][1]*v1 + K[0][2]*v2;
    float a1 = K[1][0]*v0 + K[1][1]*v1 + K[1][2]*v2;
    float a2 = K[2][0]*v0 + K[2][1]*v1 + K[2][2]*v2;
    float si = sqrtf(a0*a0 + a1*a1 + a2*a2);
    float zs = zi[i] / fmaxf(si, 1e-20f);
    Rm[0][0]+=zs*v0*a0; Rm[0][1]+=zs*v0*a1; Rm[0][2]+=zs*v0*a2;
    Rm[1][0]+=zs*v1*a0; Rm[1][1]+=zs*v1*a1; Rm[1][2]+=zs*v1*a2;
    Rm[2][0]+=zs*v2*a0; Rm[2][1]+=zs*v2*a1; Rm[2][2]+=zs*v2*a2;
    trRK += zi[i] * si;
  }
  float scale = trRK / var1;
  float t0 = mu2x - scale*(Rm[0][0]*mu1x + Rm[0][1]*mu1y + Rm[0][2]*mu1z);
  float t1 = mu2y - scale*(Rm[1][0]*mu1x + Rm[1][1]*mu1y + Rm[1][2]*mu1z);
  float t2 = mu2z - scale*(Rm[2][0]*mu1x + Rm[2][1]*mu1y + Rm[2][2]*mu1z);

  float errsum = 0.f;
  #pragma unroll
  for (int g = 0; g < 6; ++g) {
    float4 p0 = Pr[g*3+0], p1 = Pr[g*3+1], p2 = Pr[g*3+2];
    float px[4][3] = {{p0.x,p0.y,p0.z},{p0.w,p1.x,p1.y},
                      {p1.z,p1.w,p2.x},{p2.y,p2.z,p2.w}};
    #pragma unroll
    for (int q = 0; q < 4; ++q) {
      float4 gg = Gr[g*4+q];
      float X = px[q][0], Y = px[q][1], Z = px[q][2];
      float q0 = scale*(Rm[0][0]*X + Rm[0][1]*Y + Rm[0][2]*Z) + t0;
      float q1 = scale*(Rm[1][0]*X + Rm[1][1]*Y + Rm[1][2]*Z) + t1;
      float q2 = scale*(Rm[2][0]*X + Rm[2][1]*Y + Rm[2][2]*Z) + t2;
      float d0 = q0 - gg.x, d1 = q1 - gg.y, d2 = q2 - gg.z;
      errsum += sqrtf(d0*d0 + d1*d1 + d2*d2);
    }
  }
  return errsum;
}

__global__ __launch_bounds__(256) void bmp_main(
    const float*  __restrict__ pred_rotmat, const float* __restrict__ pred_camera,
    const float*  __restrict__ pred_joints, const float4* __restrict__ pred_verts,
    const float*  __restrict__ pred_betas,  const float* __restrict__ gt_rotmat,
    const float*  __restrict__ gt_shape,    const float* __restrict__ gt_kp2d,
    const float*  __restrict__ gt_kp3d,     const float4* __restrict__ gt_verts,
    const int*    __restrict__ has_smpl,    double* __restrict__ ws) {
  const int bid = blockIdx.x;
  const int tid = threadIdx.x;

  if (bid >= B_VERT) {                       // ---- vertex |diff| stream ----
    float acc = 0.f;
    for (int i = (bid - B_VERT) * 256 + tid; i < NV4; i += VBLK * 256) {
      float4 a = pred_verts[i];
      float4 b = gt_verts[i];
      int e  = i * 4;
      int b0 = e / PER_B;
      int b3 = (e + 3) / PER_B;
      if (b0 == b3) {
        if (has_smpl[b0] > 0)
          acc += fabsf(a.x-b.x) + fabsf(a.y-b.y) + fabsf(a.z-b.z) + fabsf(a.w-b.w);
      } else {
        float d[4] = {fabsf(a.x-b.x), fabsf(a.y-b.y), fabsf(a.z-b.z), fabsf(a.w-b.w)};
        #pragma unroll
        for (int c = 0; c < 4; ++c) {
          int bb = (e + c) / PER_B;
          if (has_smpl[bb] > 0) acc += d[c];
        }
      }
    }
    block_sum_store(acc, &ws[bid]);
    return;
  }

  if (bid >= B_POSE) {                       // ---- pose: mask*(dR)^2 ----
    int idx = (bid - B_POSE) * 256 + tid;    // < 110592
    int b   = idx / 216;
    float m = (has_smpl[b] > 0) ? 1.f : 0.f;
    float d = pred_rotmat[idx] - gt_rotmat[idx];
    block_sum_store(m * d * d, &ws[bid]);
    return;
  }

  if (bid >= B_KP3D) {                       // ---- kp3d ----
    int idx = (bid - B_KP3D) * 256 + tid;    // < 12288
    int b = idx / 24, j = idx - (idx / 24) * 24;
    const float* PJ = pred_joints + b * 72;
    const float* G  = gt_kp3d + b * 96;
    float cf = G[j*4+3];
    float ssum = 0.f;
    #pragma unroll
    for (int c = 0; c < 3; ++c) {
      float prp = 0.5f * (PJ[2*3+c] + PJ[3*3+c]);
      float gtp = 0.5f * (G[2*4+c] + G[3*4+c]);
      ssum += fabsf((PJ[j*3+c] - prp) - (G[j*4+c] - gtp));
    }
    block_sum_store(cf * ssum, &ws[bid]);
    return;
  }

  if (bid >= B_KP2D) {                       // ---- kp2d ----
    int idx = (bid - B_KP2D) * 256 + tid;    // < 12288
    int b = idx / 24, j = idx - (idx / 24) * 24;
    float cam0 = pred_camera[b*3+0], cam1 = pred_camera[b*3+1], cam2 = pred_camera[b*3+2];
    float depth = 2.f * 1000.f / (EPSF + cam0 * 512.f);
    float px = pred_joints[(b*24+j)*3+0] + cam1;
    float py = pred_joints[(b*24+j)*3+1] + cam2;
    float pz = pred_joints[(b*24+j)*3+2] + depth;
    float kxn = (1000.f * px / pz + 256.f) * (1.f / 512.f);
    float kyn = (1000.f * py / pz + 256.f) * (1.f / 512.f);
    float gx = gt_kp2d[(b*24+j)*3+0] * (1.f / 512.f);
    float gy = gt_kp2d[(b*24+j)*3+1] * (1.f / 512.f);
    float cf = gt_kp2d[(b*24+j)*3+2];
    block_sum_store(cf * (fabsf(kxn - gx) + fabsf(kyn - gy)), &ws[bid]);
    return;
  }

  if (bid >= B_BETA) {                       // ---- betas ----
    int idx = (bid - B_BETA) * 256 + tid;    // < 5120
    int b = idx / 10;
    float m = (has_smpl[b] > 0) ? 1.f : 0.f;
    float d = pred_betas[idx] - gt_shape[idx];
    block_sum_store(m * d * d, &ws[bid]);
    return;
  }

  if (bid >= B_NV) {                         // ---- n_valid ----
    int idx = (bid - B_NV) * 256 + tid;      // < 512
    block_sum_store((has_smpl[idx] > 0) ? 1.f : 0.f, &ws[bid]);
    return;
  }

  {                                          // ---- Procrustes (8 blocks) ----
    float e = 0.f;
    if (tid < 64) {
      int b = bid * 64 + tid;                // < 512
      e = procrustes_err((const float4*)pred_joints, (const float4*)gt_kp3d, b);
    }
    block_sum_store(e, &ws[bid]);
  }
}

__global__ __launch_bounds__(256) void bmp_finalize(const double* __restrict__ ws,
                                                    float* __restrict__ out) {
  const int tid = threadIdx.x;
  double s[7] = {0,0,0,0,0,0,0};
  for (int i = tid; i < NBLK; i += 256) {
    double v = ws[i];
    int slot;
    if      (i >= B_VERT) slot = 0;   // shape
    else if (i >= B_POSE) slot = 1;   // pose
    else if (i >= B_KP3D) slot = 2;   // kp3d
    else if (i >= B_KP2D) slot = 3;   // kp2d
    else if (i >= B_BETA) slot = 4;   // betas
    else if (i >= B_NV)   slot = 5;   // nvalid
    else                  slot = 6;   // pa
    s[slot] += v;
  }
  #pragma unroll
  for (int k = 0; k < 7; ++k)
    #pragma unroll
    for (int off = 32; off > 0; off >>= 1) s[k] += __shfl_down(s[k], off);
  __shared__ double red[4][7];
  const int lane = tid & 63, wid = tid >> 6;
  if (lane == 0)
    #pragma unroll
    for (int k = 0; k < 7; ++k) red[wid][k] = s[k];
  __syncthreads();
  if (tid == 0) {
    double t[7];
    #pragma unroll
    for (int k = 0; k < 7; ++k) t[k] = red[0][k]+red[1][k]+red[2][k]+red[3][k];
    double nv = t[5];
    double loss_kp2d  = t[3] / 24576.0;              // 512*24*2
    double loss_kp3d  = t[2] / 36864.0;              // 512*24*3
    double loss_shape = t[0] / (nv * 20670.0 + 1e-8);
    double loss_pose  = t[1] / (nv * 216.0   + 1e-8);
    double loss_betas = t[4] / (nv * 10.0    + 1e-8);
    double pa         = t[6] / 12288.0;              // 512*24
    out[0] = (float)(4.0*loss_kp2d + 4.0*loss_kp3d + loss_shape + loss_pose
                     + 0.01*loss_betas + pa);
  }
}

extern "C" void kernel_launch(void* const* d_in, const int* in_sizes, int n_in,
                              void* d_out, int out_size, void* d_ws, size_t ws_size,
                              hipStream_t stream) {
  const float*  pred_rotmat = (const float*)d_in[0];
  const float*  pred_camera = (const float*)d_in[1];
  const float*  pred_joints = (const float*)d_in[2];
  const float4* pred_verts  = (const float4*)d_in[3];
  const float*  pred_betas  = (const float*)d_in[4];
  const float*  gt_rotmat   = (const float*)d_in[5];
  const float*  gt_shape    = (const float*)d_in[6];
  const float*  gt_kp2d     = (const float*)d_in[7];
  const float*  gt_kp3d     = (const float*)d_in[8];
  const float4* gt_verts    = (const float4*)d_in[9];
  const int*    has_smpl    = (const int*)d_in[10];
  double* ws = (double*)d_ws;

  bmp_main<<<NBLK, 256, 0, stream>>>(pred_rotmat, pred_camera, pred_joints,
      pred_verts, pred_betas, gt_rotmat, gt_shape, gt_kp2d, gt_kp3d, gt_verts,
      has_smpl, ws);
  bmp_finalize<<<1, 256, 0, stream>>>(ws, (float*)d_out);
}

// Round 3
// 128.201 us; speedup vs baseline: 1.2437x; 1.1570x over previous
//
#include <hip/hip_runtime.h>
#include <math.h>

#define EPSF   1e-8f
#define NV4    2645760   // 512*6890*3 / 4
#define PER_B  20670     // 6890*3

// block-role layout. ws[bid] = this block's partial (double). No atomics, no init.
#define B_PROC   0      // 8 blocks, 64 active threads each -> 512 batches
#define B_NV     8      // 2 blocks
#define B_BETA   10     // 20 blocks (5120)
#define B_KP2D   30     // 48 blocks (12288)
#define B_KP3D   78     // 48 blocks (12288)
#define B_POSE   126    // 108 blocks (27648 float4)
#define B_VERT   234    // 1292 blocks (2048 float4 chunks)
#define NBLK     1526

__device__ __forceinline__ float frcp(float x)  { return __builtin_amdgcn_rcpf(x); }
__device__ __forceinline__ float frsq(float x)  { return __builtin_amdgcn_rsqf(x); }
__device__ __forceinline__ float fsqrt(float x) { return __builtin_amdgcn_sqrtf(x); }

__device__ __forceinline__ void block_sum_store(float v, double* dst) {
  #pragma unroll
  for (int off = 32; off > 0; off >>= 1) v += __shfl_down(v, off);
  __shared__ float red[4];
  const int lane = threadIdx.x & 63;
  const int wid  = threadIdx.x >> 6;
  if (lane == 0) red[wid] = v;
  __syncthreads();
  if (threadIdx.x == 0) *dst = (double)(red[0] + red[1] + red[2] + red[3]);
}

// one Jacobi rotation on symmetric A zeroing A[P][Q]; accumulates V <- V*J
template<int P, int Q>
__device__ __forceinline__ void jrot(float A[3][3], float Vv[3][3]) {
  float apq = A[P][Q];
  if (fabsf(apq) < 1e-20f) return;
  float tau = (A[Q][Q] - A[P][P]) * 0.5f * frcp(apq);
  float t   = copysignf(1.f, tau) * frcp(fabsf(tau) + fsqrt(1.f + tau * tau));
  float c   = frsq(1.f + t * t);
  float s   = t * c;
  float cP[3], cQ[3];
  #pragma unroll
  for (int k = 0; k < 3; ++k) { cP[k] = c*A[k][P] - s*A[k][Q]; cQ[k] = s*A[k][P] + c*A[k][Q]; }
  #pragma unroll
  for (int k = 0; k < 3; ++k) { A[k][P] = cP[k]; A[k][Q] = cQ[k]; }
  float rP[3], rQ[3];
  #pragma unroll
  for (int k = 0; k < 3; ++k) { rP[k] = c*A[P][k] - s*A[Q][k]; rQ[k] = s*A[P][k] + c*A[Q][k]; }
  #pragma unroll
  for (int k = 0; k < 3; ++k) { A[P][k] = rP[k]; A[Q][k] = rQ[k]; }
  #pragma unroll
  for (int k = 0; k < 3; ++k) {
    float vp = c*Vv[k][P] - s*Vv[k][Q];
    Vv[k][Q] = s*Vv[k][P] + c*Vv[k][Q];
    Vv[k][P] = vp;
  }
}

#define CSWAP(I, J)                                                        \
  if (lam[I] < lam[J]) {                                                   \
    float tl = lam[I]; lam[I] = lam[J]; lam[J] = tl;                       \
    _Pragma("unroll")                                                      \
    for (int r = 0; r < 3; ++r) {                                          \
      float tv = Vv[r][I]; Vv[r][I] = Vv[r][J]; Vv[r][J] = tv;             \
    }                                                                      \
  }

// per-batch Procrustes via float4 gathers; single-pass moments, re-load for error
__device__ float procrustes_err(const float4* __restrict__ P4,
                                const float4* __restrict__ G4, int b) {
  const float4* Pr = P4 + b * 18;   // 24 joints * 3 = 18 float4
  const float4* Gr = G4 + b * 24;   // 24 joints * 4 = 24 float4

  float sx0=0,sx1=0,sx2=0, sy0=0,sy1=0,sy2=0, sxx=0;
  float Ku[3][3] = {{0,0,0},{0,0,0},{0,0,0}};
  #pragma unroll
  for (int g = 0; g < 6; ++g) {
    float4 p0 = Pr[g*3+0], p1 = Pr[g*3+1], p2 = Pr[g*3+2];
    float px[4][3] = {{p0.x,p0.y,p0.z},{p0.w,p1.x,p1.y},
                      {p1.z,p1.w,p2.x},{p2.y,p2.z,p2.w}};
    #pragma unroll
    for (int q = 0; q < 4; ++q) {
      float4 gg = Gr[g*4+q];
      float x0 = px[q][0], x1 = px[q][1], x2 = px[q][2];
      sx0 += x0; sx1 += x1; sx2 += x2;
      sy0 += gg.x; sy1 += gg.y; sy2 += gg.z;
      sxx += x0*x0 + x1*x1 + x2*x2;
      Ku[0][0]+=x0*gg.x; Ku[0][1]+=x0*gg.y; Ku[0][2]+=x0*gg.z;
      Ku[1][0]+=x1*gg.x; Ku[1][1]+=x1*gg.y; Ku[1][2]+=x1*gg.z;
      Ku[2][0]+=x2*gg.x; Ku[2][1]+=x2*gg.y; Ku[2][2]+=x2*gg.z;
    }
  }
  const float inv24 = 1.f / 24.f;
  float mu1x=sx0*inv24, mu1y=sx1*inv24, mu1z=sx2*inv24;
  float mu2x=sy0*inv24, mu2y=sy1*inv24, mu2z=sy2*inv24;
  float m1v[3] = {mu1x, mu1y, mu1z};
  float m2v[3] = {mu2x, mu2y, mu2z};
  float K[3][3];
  #pragma unroll
  for (int r = 0; r < 3; ++r)
    #pragma unroll
    for (int c = 0; c < 3; ++c)
      K[r][c] = Ku[r][c] - 24.f * m1v[r] * m2v[c] + EPSF;
  float var1 = sxx - 24.f * (mu1x*mu1x + mu1y*mu1y + mu1z*mu1z);

  float detK = K[0][0]*(K[1][1]*K[2][2]-K[1][2]*K[2][1])
             - K[0][1]*(K[1][0]*K[2][2]-K[1][2]*K[2][0])
             + K[0][2]*(K[1][0]*K[2][1]-K[1][1]*K[2][0]);
  float sgn = (detK > 0.f) ? 1.f : ((detK < 0.f) ? -1.f : 0.f);

  float A[3][3];
  #pragma unroll
  for (int r = 0; r < 3; ++r)
    #pragma unroll
    for (int c = 0; c < 3; ++c)
      A[r][c] = K[0][r]*K[0][c] + K[1][r]*K[1][c] + K[2][r]*K[2][c];

  float Vv[3][3] = {{1,0,0},{0,1,0},{0,0,1}};
  for (int sweep = 0; sweep < 8; ++sweep) {
    jrot<0,1>(A, Vv); jrot<0,2>(A, Vv); jrot<1,2>(A, Vv);
  }
  float lam[3] = {A[0][0], A[1][1], A[2][2]};
  CSWAP(0,1) CSWAP(0,2) CSWAP(1,2)

  float Rm[3][3] = {{0,0,0},{0,0,0},{0,0,0}};
  float zi[3] = {1.f, 1.f, sgn};
  float trRK = 0.f;
  #pragma unroll
  for (int i = 0; i < 3; ++i) {
    float v0 = Vv[0][i], v1 = Vv[1][i], v2 = Vv[2][i];
    float a0 = K[0][0]*v0 + K[0][1]*v1 + K[0][2]*v2;
    float a1 = K[1][0]*v0 + K[1][1]*v1 + K[1][2]*v2;
    float a2 = K[2][0]*v0 + K[2][1]*v1 + K[2][2]*v2;
    float s2 = a0*a0 + a1*a1 + a2*a2;
    float si = fsqrt(s2);
    float zs = zi[i] * frcp(fmaxf(si, 1e-20f));
    Rm[0][0]+=zs*v0*a0; Rm[0][1]+=zs*v0*a1; Rm[0][2]+=zs*v0*a2;
    Rm[1][0]+=zs*v1*a0; Rm[1][1]+=zs*v1*a1; Rm[1][2]+=zs*v1*a2;
    Rm[2][0]+=zs*v2*a0; Rm[2][1]+=zs*v2*a1; Rm[2][2]+=zs*v2*a2;
    trRK += zi[i] * si;
  }
  float scale = trRK * frcp(var1);
  float t0 = mu2x - scale*(Rm[0][0]*mu1x + Rm[0][1]*mu1y + Rm[0][2]*mu1z);
  float t1 = mu2y - scale*(Rm[1][0]*mu1x + Rm[1][1]*mu1y + Rm[1][2]*mu1z);
  float t2 = mu2z - scale*(Rm[2][0]*mu1x + Rm[2][1]*mu1y + Rm[2][2]*mu1z);

  float errsum = 0.f;
  #pragma unroll
  for (int g = 0; g < 6; ++g) {
    float4 p0 = Pr[g*3+0], p1 = Pr[g*3+1], p2 = Pr[g*3+2];
    float px[4][3] = {{p0.x,p0.y,p0.z},{p0.w,p1.x,p1.y},
                      {p1.z,p1.w,p2.x},{p2.y,p2.z,p2.w}};
    #pragma unroll
    for (int q = 0; q < 4; ++q) {
      float4 gg = Gr[g*4+q];
      float X = px[q][0], Y = px[q][1], Z = px[q][2];
      float q0 = scale*(Rm[0][0]*X + Rm[0][1]*Y + Rm[0][2]*Z) + t0;
      float q1 = scale*(Rm[1][0]*X + Rm[1][1]*Y + Rm[1][2]*Z) + t1;
      float q2 = scale*(Rm[2][0]*X + Rm[2][1]*Y + Rm[2][2]*Z) + t2;
      float d0 = q0 - gg.x, d1 = q1 - gg.y, d2 = q2 - gg.z;
      errsum += fsqrt(d0*d0 + d1*d1 + d2*d2);
    }
  }
  return errsum;
}

__global__ __launch_bounds__(256) void bmp_main(
    const float4* __restrict__ pred_rot4,   const float* __restrict__ pred_camera,
    const float*  __restrict__ pred_joints, const float4* __restrict__ pred_verts,
    const float*  __restrict__ pred_betas,  const float4* __restrict__ gt_rot4,
    const float*  __restrict__ gt_shape,    const float* __restrict__ gt_kp2d,
    const float*  __restrict__ gt_kp3d,     const float4* __restrict__ gt_verts,
    const int*    __restrict__ has_smpl,    double* __restrict__ ws) {
  const int bid = blockIdx.x;
  const int tid = threadIdx.x;

  if (bid >= B_VERT) {                       // ---- vertex |diff| stream ----
    const int chunk  = bid - B_VERT;         // 0..1291
    const int f4base = chunk * 2048;
    const int nf4    = min(2048, NV4 - f4base);  // 2048 or 1792 (=7*256)
    const int e0     = f4base * 4;
    const int b0     = e0 / PER_B;
    const int blast  = (e0 + nf4 * 4 - 1) / PER_B;   // b0 or b0+1
    const int m0     = has_smpl[b0] > 0;
    const int m1     = has_smpl[blast] > 0;
    float acc = 0.f;
    if (m0 | m1) {
      const float4* __restrict__ P = pred_verts + f4base + tid;
      const float4* __restrict__ G = gt_verts  + f4base + tid;
      if (nf4 == 2048) {
        float4 pa[8], ga[8];
        #pragma unroll
        for (int k = 0; k < 8; ++k) pa[k] = P[k * 256];
        #pragma unroll
        for (int k = 0; k < 8; ++k) ga[k] = G[k * 256];
        if (m0 & m1) {
          #pragma unroll
          for (int k = 0; k < 8; ++k)
            acc += fabsf(pa[k].x-ga[k].x) + fabsf(pa[k].y-ga[k].y)
                 + fabsf(pa[k].z-ga[k].z) + fabsf(pa[k].w-ga[k].w);
        } else {                             // one side of boundary masked out
          const int   bnd = (b0 + 1) * PER_B;
          const float fm0 = m0 ? 1.f : 0.f;
          const float fm1 = m1 ? 1.f : 0.f;
          #pragma unroll
          for (int k = 0; k < 8; ++k) {
            int e = (f4base + tid + k * 256) * 4;
            acc += ((e+0) >= bnd ? fm1 : fm0) * fabsf(pa[k].x-ga[k].x)
                 + ((e+1) >= bnd ? fm1 : fm0) * fabsf(pa[k].y-ga[k].y)
                 + ((e+2) >= bnd ? fm1 : fm0) * fabsf(pa[k].z-ga[k].z)
                 + ((e+3) >= bnd ? fm1 : fm0) * fabsf(pa[k].w-ga[k].w);
          }
        }
      } else {                               // last chunk: single batch, m0 set
        #pragma unroll
        for (int k = 0; k < 7; ++k) {
          float4 a = P[k * 256], b = G[k * 256];
          acc += fabsf(a.x-b.x) + fabsf(a.y-b.y) + fabsf(a.z-b.z) + fabsf(a.w-b.w);
        }
      }
    }
    block_sum_store(acc, &ws[bid]);
    return;
  }

  if (bid >= B_POSE) {                       // ---- pose: mask*(dR)^2, float4 ----
    int idx = (bid - B_POSE) * 256 + tid;    // < 27648
    int b   = idx / 54;                      // 216 floats = 54 float4 per batch
    float m = (has_smpl[b] > 0) ? 1.f : 0.f;
    float4 p = pred_rot4[idx], g = gt_rot4[idx];
    float dx = p.x-g.x, dy = p.y-g.y, dz = p.z-g.z, dw = p.w-g.w;
    block_sum_store(m * (dx*dx + dy*dy + dz*dz + dw*dw), &ws[bid]);
    return;
  }

  if (bid >= B_KP3D) {                       // ---- kp3d ----
    int idx = (bid - B_KP3D) * 256 + tid;    // < 12288
    int b = idx / 24, j = idx - (idx / 24) * 24;
    const float* PJ = pred_joints + b * 72;
    const float* G  = gt_kp3d + b * 96;
    float cf = G[j*4+3];
    float ssum = 0.f;
    #pragma unroll
    for (int c = 0; c < 3; ++c) {
      float prp = 0.5f * (PJ[2*3+c] + PJ[3*3+c]);
      float gtp = 0.5f * (G[2*4+c] + G[3*4+c]);
      ssum += fabsf((PJ[j*3+c] - prp) - (G[j*4+c] - gtp));
    }
    block_sum_store(cf * ssum, &ws[bid]);
    return;
  }

  if (bid >= B_KP2D) {                       // ---- kp2d ----
    int idx = (bid - B_KP2D) * 256 + tid;    // < 12288
    int b = idx / 24, j = idx - (idx / 24) * 24;
    float cam0 = pred_camera[b*3+0], cam1 = pred_camera[b*3+1], cam2 = pred_camera[b*3+2];
    float depth = 2.f * 1000.f / (EPSF + cam0 * 512.f);
    float px = pred_joints[(b*24+j)*3+0] + cam1;
    float py = pred_joints[(b*24+j)*3+1] + cam2;
    float pz = pred_joints[(b*24+j)*3+2] + depth;
    float kxn = (1000.f * px / pz + 256.f) * (1.f / 512.f);
    float kyn = (1000.f * py / pz + 256.f) * (1.f / 512.f);
    float gx = gt_kp2d[(b*24+j)*3+0] * (1.f / 512.f);
    float gy = gt_kp2d[(b*24+j)*3+1] * (1.f / 512.f);
    float cf = gt_kp2d[(b*24+j)*3+2];
    block_sum_store(cf * (fabsf(kxn - gx) + fabsf(kyn - gy)), &ws[bid]);
    return;
  }

  if (bid >= B_BETA) {                       // ---- betas ----
    int idx = (bid - B_BETA) * 256 + tid;    // < 5120
    int b = idx / 10;
    float m = (has_smpl[b] > 0) ? 1.f : 0.f;
    float d = pred_betas[idx] - gt_shape[idx];
    block_sum_store(m * d * d, &ws[bid]);
    return;
  }

  if (bid >= B_NV) {                         // ---- n_valid ----
    int idx = (bid - B_NV) * 256 + tid;      // < 512
    block_sum_store((has_smpl[idx] > 0) ? 1.f : 0.f, &ws[bid]);
    return;
  }

  {                                          // ---- Procrustes (8 blocks) ----
    float e = 0.f;
    if (tid < 64) {
      int b = bid * 64 + tid;                // < 512
      e = procrustes_err((const float4*)pred_joints, (const float4*)gt_kp3d, b);
    }
    block_sum_store(e, &ws[bid]);
  }
}

__global__ __launch_bounds__(256) void bmp_finalize(const double* __restrict__ ws,
                                                    float* __restrict__ out) {
  const int tid = threadIdx.x;
  double s[7] = {0,0,0,0,0,0,0};
  for (int i = tid; i < NBLK; i += 256) {
    double v = ws[i];
    int slot;
    if      (i >= B_VERT) slot = 0;   // shape
    else if (i >= B_POSE) slot = 1;   // pose
    else if (i >= B_KP3D) slot = 2;   // kp3d
    else if (i >= B_KP2D) slot = 3;   // kp2d
    else if (i >= B_BETA) slot = 4;   // betas
    else if (i >= B_NV)   slot = 5;   // nvalid
    else                  slot = 6;   // pa
    s[slot] += v;
  }
  #pragma unroll
  for (int k = 0; k < 7; ++k)
    #pragma unroll
    for (int off = 32; off > 0; off >>= 1) s[k] += __shfl_down(s[k], off);
  __shared__ double red[4][7];
  const int lane = tid & 63, wid = tid >> 6;
  if (lane == 0)
    #pragma unroll
    for (int k = 0; k < 7; ++k) red[wid][k] = s[k];
  __syncthreads();
  if (tid == 0) {
    double t[7];
    #pragma unroll
    for (int k = 0; k < 7; ++k) t[k] = red[0][k]+red[1][k]+red[2][k]+red[3][k];
    double nv = t[5];
    double loss_kp2d  = t[3] / 24576.0;              // 512*24*2
    double loss_kp3d  = t[2] / 36864.0;              // 512*24*3
    double loss_shape = t[0] / (nv * 20670.0 + 1e-8);
    double loss_pose  = t[1] / (nv * 216.0   + 1e-8);
    double loss_betas = t[4] / (nv * 10.0    + 1e-8);
    double pa         = t[6] / 12288.0;              // 512*24
    out[0] = (float)(4.0*loss_kp2d + 4.0*loss_kp3d + loss_shape + loss_pose
                     + 0.01*loss_betas + pa);
  }
}

extern "C" void kernel_launch(void* const* d_in, const int* in_sizes, int n_in,
                              void* d_out, int out_size, void* d_ws, size_t ws_size,
                              hipStream_t stream) {
  const float4* pred_rot4   = (const float4*)d_in[0];
  const float*  pred_camera = (const float*)d_in[1];
  const float*  pred_joints = (const float*)d_in[2];
  const float4* pred_verts  = (const float4*)d_in[3];
  const float*  pred_betas  = (const float*)d_in[4];
  const float4* gt_rot4     = (const float4*)d_in[5];
  const float*  gt_shape    = (const float*)d_in[6];
  const float*  gt_kp2d     = (const float*)d_in[7];
  const float*  gt_kp3d     = (const float*)d_in[8];
  const float4* gt_verts    = (const float4*)d_in[9];
  const int*    has_smpl    = (const int*)d_in[10];
  double* ws = (double*)d_ws;

  bmp_main<<<NBLK, 256, 0, stream>>>(pred_rot4, pred_camera, pred_joints,
      pred_verts, pred_betas, gt_rot4, gt_shape, gt_kp2d, gt_kp3d, gt_verts,
      has_smpl, ws);
  bmp_finalize<<<1, 256, 0, stream>>>(ws, (float*)d_out);
}